// Round 12
// baseline (473.432 us; speedup 1.0000x reference)
//
#include <hip/hip_runtime.h>
#include <hip/hip_bf16.h>
#include <math.h>

#define NN 20000
#define EE 320000
#define IND 128
#define HH 6
#define CC 64
#define HCC 384
#define NCC 16
#define NGG 64

typedef __bf16 bf16x8 __attribute__((ext_vector_type(8)));
typedef float f32x4 __attribute__((ext_vector_type(4)));
typedef float f32x2 __attribute__((ext_vector_type(2)));
typedef unsigned short ushort_t;
typedef unsigned int uint_t;

#define LOG2E 1.44269504088896f

__device__ inline ushort_t f2bf(float f) {
    union { float f; uint_t u; } x; x.f = f;
    uint_t r = (x.u + 0x7FFF + ((x.u >> 16) & 1)) >> 16;
    return (ushort_t)r;
}
// 8 packed bf16 (uint4) -> 4 f32x2 (pairs) for packed-f32 VALU
__device__ inline void bf8cvt2(uint4 v, f32x2* f) {
    union { uint_t u; float x; } a, b;
    a.u = v.x << 16; b.u = v.x & 0xFFFF0000u; f[0] = (f32x2){a.x, b.x};
    a.u = v.y << 16; b.u = v.y & 0xFFFF0000u; f[1] = (f32x2){a.x, b.x};
    a.u = v.z << 16; b.u = v.z & 0xFFFF0000u; f[2] = (f32x2){a.x, b.x};
    a.u = v.w << 16; b.u = v.w & 0xFFFF0000u; f[3] = (f32x2){a.x, b.x};
}

// DPP cross-lane add (VALU, no DS pipe). CTRL: 0xB1=xor1, 0x4E=xor2,
// 0x141=row_half_mirror (==xor4 once quad-uniform), 0x140=row_mirror (==xor8).
template <int CTRL>
__device__ inline float dppadd(float x) {
    int y = __builtin_amdgcn_mov_dpp(__builtin_bit_cast(int, x), CTRL, 0xF, 0xF, true);
    return x + __builtin_bit_cast(float, y);
}

// async global->LDS: lane L writes lds+16*L
__device__ inline void load_lds16(const ushort_t* g, ushort_t* l) {
    __builtin_amdgcn_global_load_lds(
        (const __attribute__((address_space(1))) void*)g,
        (__attribute__((address_space(3))) void*)l, 16, 0, 0);
}

// bijective XCD swizzle (m204): consecutive logical ids land on the SAME XCD.
__device__ inline int xcd_swz(int lin, int nwg) {
    int q = nwg >> 3, r = nwg & 7;
    int xc = lin & 7, j = lin >> 3;
    return (xc < r ? xc * (q + 1) : r * (q + 1) + (xc - r) * q) + j;
}

// ---------------- utility kernels ----------------

__global__ void zero_init_kernel(int* counts, int* srcs_tail, int* dhist,
                                 float* pooled, int n, int np) {
    int t = blockIdx.x * blockDim.x + threadIdx.x;
    if (t < n) counts[t] = 0;
    if (t < np) pooled[t] = 0.0f;
    if (t < 32) srcs_tail[t] = 0;    // pad covers gat1's 16-edge group over-read
    if (t < 256) dhist[t] = 0;
}

__global__ void count_kernel(const int* __restrict__ ei, int* __restrict__ counts, int E) {
    int t = blockIdx.x * blockDim.x + threadIdx.x;
    if (t < E) atomicAdd(&counts[ei[E + t]], 1);
}

// distributed scan phase 1: per-block exclusive scan of (counts+1); block totals out.
// Also builds the degree histogram for the straggler-first node ordering.
__global__ __launch_bounds__(256) void scan_local_kernel(
    const int* __restrict__ counts, int* __restrict__ offsets,
    int* __restrict__ blockSums, int* __restrict__ dhist, int n) {
    __shared__ int lp[256];
    int t = threadIdx.x, b = blockIdx.x;
    int i = b * 256 + t;
    int c = (i < n) ? counts[i] : 0;
    int v = (i < n) ? c + 1 : 0;
    if (i < n) atomicAdd(&dhist[min(c, 255)], 1);
    lp[t] = v;
    __syncthreads();
    for (int o = 1; o < 256; o <<= 1) {
        int u = (t >= o) ? lp[t - o] : 0;
        __syncthreads();
        lp[t] += u;
        __syncthreads();
    }
    if (t == 255) blockSums[b] = lp[255];
    if (i < n) offsets[i] = lp[t] - v;   // block-local exclusive
}

// phase 2: add scanned block prefix, finalize offsets + cursor.
__global__ __launch_bounds__(256) void scan_fixup_kernel(
    const int* __restrict__ blockSums,
    int* __restrict__ offsets, int* __restrict__ cursor, int n, int nb) {
    __shared__ int red[256];
    int t = threadIdx.x, b = blockIdx.x;
    red[t] = (t < b) ? blockSums[t] : 0;
    __syncthreads();
    for (int o = 128; o > 0; o >>= 1) {
        if (t < o) red[t] += red[t + o];
        __syncthreads();
    }
    int prefix = red[0];
    int i = b * 256 + t;
    if (i < n) {
        int val = offsets[i] + prefix;
        offsets[i] = val;
        cursor[i] = val;
    }
    if (b == nb - 1 && t == 0) offsets[n] = prefix + blockSums[b];
}

// descending-degree bucket bases: dcur[b] = #nodes with bucket > b (exclusive suffix sum).
__global__ __launch_bounds__(256) void dscan_kernel(const int* __restrict__ dhist,
                                                    int* __restrict__ dcur) {
    __shared__ int lp[256];
    int t = threadIdx.x;
    int h = dhist[255 - t];
    lp[t] = h;
    __syncthreads();
    for (int o = 1; o < 256; o <<= 1) {
        int u = (t >= o) ? lp[t - o] : 0;
        __syncthreads();
        lp[t] += u;
        __syncthreads();
    }
    dcur[255 - t] = lp[t] - h;
}

// scatter node ids into descending-degree order (straggler-first dispatch for gat kernels)
__global__ void order_kernel(const int* __restrict__ counts, int* __restrict__ dcur,
                             int* __restrict__ order, int n) {
    int t = blockIdx.x * blockDim.x + threadIdx.x;
    if (t < n) {
        int b = min(counts[t], 255);
        int slot = atomicAdd(&dcur[b], 1);
        order[slot] = t;
    }
}

// fill: single srcs array storing s<<8 (byte offset for 256B rows); gat6 derives *6.
__global__ void fill_kernel(const int* __restrict__ ei, int* __restrict__ cursor,
                            int* __restrict__ srcs, int E, int n) {
    int t = blockIdx.x * blockDim.x + threadIdx.x;
    if (t < E) {
        int s = ei[t];
        int d = ei[E + t];
        int slot = atomicAdd(&cursor[d], 1);
        srcs[slot] = s << 8;
    } else if (t < E + n) {
        int i = t - E;
        int slot = atomicAdd(&cursor[i], 1);
        srcs[slot] = i << 8;
    }
}

// ---------------- weight/input prep: fp32 -> bf16 TRANSPOSED ([N][K]) ----------------
#define WBIG (1152 * IND)
#define WC1 (768 * HCC)
#define WC2 (192 * HCC)
#define XB_N (NN * IND)
#define PREP_TOTAL (WBIG + WC1 + WC2 + XB_N + 1152 + 768 + 192)

__global__ void prep_kernel(const float* __restrict__ x, const float* __restrict__ inp_w,
    const float* __restrict__ l0wl, const float* __restrict__ l0wr,
    const float* __restrict__ l1wl, const float* __restrict__ l1wr,
    const float* __restrict__ l2wl, const float* __restrict__ l2wr,
    const float* __restrict__ resw,
    const float* __restrict__ inp_b,
    const float* __restrict__ l0bl, const float* __restrict__ l0br,
    const float* __restrict__ l1bl, const float* __restrict__ l1br,
    const float* __restrict__ l2bl, const float* __restrict__ l2br,
    ushort_t* wBig, ushort_t* wC1, ushort_t* wC2, ushort_t* xb,
    float* bBig, float* bC1, float* bC2)
{
    int i = blockIdx.x * blockDim.x + threadIdx.x;
    if (i >= PREP_TOTAL) return;
    if (i < WBIG) {
        int col = i >> 7, k = i & 127;
        float v;
        if (col < 384)      v = inp_w[k * 384 + col];
        else if (col < 768) v = l0wl[k * 384 + (col - 384)];
        else                v = l0wr[k * 384 + (col - 768)];
        wBig[i] = f2bf(v); return;
    }
    i -= WBIG;
    if (i < WC1) {
        int col = i / 384, k = i - col * 384;
        float v = col < 384 ? l1wl[k * 384 + col] : l1wr[k * 384 + (col - 384)];
        wC1[i] = f2bf(v); return;
    }
    i -= WC1;
    if (i < WC2) {
        int col = i / 384, k = i - col * 384;
        float v;
        if (col < 64)       v = resw[k * 64 + col];
        else if (col < 128) v = l2wl[k * 64 + (col - 64)];
        else                v = l2wr[k * 64 + (col - 128)];
        wC2[i] = f2bf(v); return;
    }
    i -= WC2;
    if (i < XB_N) { xb[i] = f2bf(x[i]); return; }
    i -= XB_N;
    if (i < 1152) {
        float v;
        if (i < 384)      v = inp_b[i];
        else if (i < 768) v = l0bl[i - 384];
        else              v = l0br[i - 768];
        bBig[i] = v; return;
    }
    i -= 1152;
    if (i < 768) { bC1[i] = i < 384 ? l1bl[i] : l1br[i - 384]; return; }
    i -= 768;
    if (i < 192) {
        float v;
        if (i < 64)       v = 0.0f;
        else if (i < 128) v = l2bl[i - 64];
        else              v = l2br[i - 128];
        bC2[i] = v; return;
    }
}

// ---------------- bf16 MFMA GEMM (128-tile, 4 waves): ALL gemms ----------------
__global__ __launch_bounds__(256) void gemm_mfma(
    const ushort_t* __restrict__ A, const ushort_t* __restrict__ BT,
    const float* __restrict__ bias,
    float* __restrict__ Cf, ushort_t* __restrict__ Cb1, int ld1,
    ushort_t* __restrict__ Cb2, int ld2, int split,
    int M, int N, int K)
{
    __shared__ ushort_t Bs[2][2][128 * 32];
    int t = threadIdx.x;
    int w = t >> 6, L = t & 63;
    int nwg = gridDim.x * gridDim.y;
    int logical = xcd_swz(blockIdx.y * gridDim.x + blockIdx.x, nwg);
    int m0 = (logical / gridDim.y) * 128;     // A-sharing group consecutive -> same XCD
    int n0 = (logical % gridDim.y) * 128;
    int q = L >> 4, r16 = L & 15;

    f32x4 acc[2][8];
#pragma unroll
    for (int a = 0; a < 2; ++a)
#pragma unroll
        for (int b = 0; b < 8; ++b) acc[a][b] = (f32x4){0.f, 0.f, 0.f, 0.f};

    int lr = L >> 2;
    int lc = ((L & 3) ^ ((lr >> 1) & 3)) * 8;
    int rB0 = min(n0 + w * 32 + lr, N - 1);
    int rB1 = min(n0 + w * 32 + 16 + lr, N - 1);
    const ushort_t* gB0 = BT + (size_t)rB0 * K + lc;
    const ushort_t* gB1 = BT + (size_t)rB1 * K + lc;
    int oB0 = (w * 32) * 32;
    int oB1 = (w * 32 + 16) * 32;

    int rA0 = min(m0 + w * 32 + r16, M - 1);
    int rA1 = min(m0 + w * 32 + 16 + r16, M - 1);
    const ushort_t* pA0 = A + (size_t)rA0 * K + q * 8;
    const ushort_t* pA1 = A + (size_t)rA1 * K + q * 8;

    int sw = (q ^ ((r16 >> 1) & 3)) * 8;

    load_lds16(gB0, &Bs[0][0][oB0]);
    load_lds16(gB1, &Bs[0][0][oB1]);
    load_lds16(gB0 + 32, &Bs[0][1][oB0]);
    load_lds16(gB1 + 32, &Bs[0][1][oB1]);
    gB0 += 64; gB1 += 64;
    bf16x8 a0 = *(const bf16x8*)pA0;
    bf16x8 a2 = *(const bf16x8*)(pA0 + 32);
    bf16x8 a1 = *(const bf16x8*)pA1;
    bf16x8 a3 = *(const bf16x8*)(pA1 + 32);
    pA0 += 64; pA1 += 64;

    int buf = 0;
    for (int k0 = 0; k0 < K; k0 += 64) {
        __syncthreads();
        bool more = (k0 + 64 < K);
        if (more) {
            int nb = buf ^ 1;
            load_lds16(gB0, &Bs[nb][0][oB0]);
            load_lds16(gB1, &Bs[nb][0][oB1]);
            load_lds16(gB0 + 32, &Bs[nb][1][oB0]);
            load_lds16(gB1 + 32, &Bs[nb][1][oB1]);
            gB0 += 64; gB1 += 64;
        }
        bf16x8 na0, na1, na2, na3;
        if (more) {
            na0 = *(const bf16x8*)pA0;
            na2 = *(const bf16x8*)(pA0 + 32);
            na1 = *(const bf16x8*)pA1;
            na3 = *(const bf16x8*)(pA1 + 32);
            pA0 += 64; pA1 += 64;
        }
#pragma unroll
        for (int ct = 0; ct < 8; ++ct) {
            bf16x8 blo = *(const bf16x8*)&Bs[buf][0][(ct * 16 + r16) * 32 + sw];
            bf16x8 bhi = *(const bf16x8*)&Bs[buf][1][(ct * 16 + r16) * 32 + sw];
            // swapped operands: lane holds row (m0+..+r16), cols q*4+reg
            acc[0][ct] = __builtin_amdgcn_mfma_f32_16x16x32_bf16(blo, a0, acc[0][ct], 0, 0, 0);
            acc[1][ct] = __builtin_amdgcn_mfma_f32_16x16x32_bf16(blo, a1, acc[1][ct], 0, 0, 0);
            acc[0][ct] = __builtin_amdgcn_mfma_f32_16x16x32_bf16(bhi, a2, acc[0][ct], 0, 0, 0);
            acc[1][ct] = __builtin_amdgcn_mfma_f32_16x16x32_bf16(bhi, a3, acc[1][ct], 0, 0, 0);
        }
        if (more) { a0 = na0; a1 = na1; a2 = na2; a3 = na3; }
        buf ^= 1;
    }
#pragma unroll
    for (int rt = 0; rt < 2; ++rt) {
        int row = m0 + w * 32 + rt * 16 + r16;
        if (row >= M) continue;
#pragma unroll
        for (int ct = 0; ct < 8; ++ct) {
            int colb = n0 + ct * 16 + q * 4;
            if (colb >= N) continue;
            float4 bv = *(const float4*)(bias + colb);
            float v0 = acc[rt][ct][0] + bv.x;
            float v1 = acc[rt][ct][1] + bv.y;
            float v2 = acc[rt][ct][2] + bv.z;
            float v3 = acc[rt][ct][3] + bv.w;
            if (colb < split) {
                if (Cf) {
                    *(float4*)(Cf + (size_t)row * ld1 + colb) = make_float4(v0, v1, v2, v3);
                } else {
                    uint2 pk;
                    pk.x = (uint_t)f2bf(v0) | ((uint_t)f2bf(v1) << 16);
                    pk.y = (uint_t)f2bf(v2) | ((uint_t)f2bf(v3) << 16);
                    *(uint2*)(Cb1 + (size_t)row * ld1 + colb) = pk;
                }
            } else {
                uint2 pk;
                pk.x = (uint_t)f2bf(v0) | ((uint_t)f2bf(v1) << 16);
                pk.y = (uint_t)f2bf(v2) | ((uint_t)f2bf(v3) << 16);
                *(uint2*)(Cb2 + (size_t)row * ld2 + (colb - split)) = pk;
            }
        }
    }
}

// ---------------- GATv2 H=6: branchless 1-deep pair loop, degree-descending order ----------------
// Blocks map wid -> order[wid] (straggler-first): high-degree nodes start earliest,
// shrinking the per-dispatch tail (r11: each extra tail cost ~6-7us).
__global__ __launch_bounds__(128) void gat6_kernel(
    const ushort_t* __restrict__ cat, const float* __restrict__ att,
    const float* __restrict__ bias, const ushort_t* __restrict__ resB,
    ushort_t* __restrict__ outB,
    const int* __restrict__ offsets, const int* __restrict__ srcs,
    const int* __restrict__ order, int n)
{
    int wid = (blockIdx.x * blockDim.x + threadIdx.x) >> 6;
    if (wid >= n) return;
    int lane = threadIdx.x & 63;
    int h = lane >> 3, c8 = lane & 7;
    bool hv = h < HH;
    int off = h * 64 + c8 * 8;
    int offL2 = (hv ? off : off - 384) * 2;   // BYTE offset; invalid lanes alias groups 0/1
    int i = __builtin_amdgcn_readfirstlane(order[wid]);
    int beg = __builtin_amdgcn_readfirstlane(offsets[i]);
    int end = __builtin_amdgcn_readfirstlane(offsets[i + 1]);
    int deg = end - beg;
    int P = (deg + 1) >> 1;
    const char* catc = (const char*)cat;

    f32x2 xr2[4], att2[4];
    {
        uint4 v = *(const uint4*)(catc + (size_t)i * 1536 + 768 + offL2);
        bf8cvt2(v, xr2);
    }
#pragma unroll
    for (int j = 0; j < 4; ++j) {
        int o = (offL2 >> 1) + 2 * j;
        att2[j] = (f32x2){att[o] * LOG2E, att[o + 1] * LOG2E};
    }

    float s = 0.0f;
    f32x2 acc2[4];
#pragma unroll
    for (int j = 0; j < 4; ++j) acc2[j] = (f32x2){0.f, 0.f};

    int bA0 = srcs[beg] * 6, bB0 = srcs[beg + 1] * 6;   // s<<8 -> s*1536
    uint4 cA = *(const uint4*)(catc + (size_t)(uint_t)bA0 + offL2);
    uint4 cB = *(const uint4*)(catc + (size_t)(uint_t)bB0 + offL2);
    int iA1 = srcs[beg + 2] * 6, iB1 = srcs[beg + 3] * 6;

    for (int p = 0; p < P; ++p) {
        uint4 nA = cA, nB = cB;
        bool pre = (p + 1 < P);       // uniform branch: skip useless last prefetch
        if (pre) {
            nA = *(const uint4*)(catc + (size_t)(uint_t)iA1 + offL2);
            nB = *(const uint4*)(catc + (size_t)(uint_t)iB1 + offL2);
            iA1 = srcs[beg + 2 * p + 4] * 6;
            iB1 = srcs[beg + 2 * p + 5] * 6;
        }
        f32x2 xlA[4], xlB[4];
        bf8cvt2(cA, xlA);
        bf8cvt2(cB, xlB);
        f32x2 pA2 = (f32x2){0.f, 0.f}, pB2 = (f32x2){0.f, 0.f};
#pragma unroll
        for (int j = 0; j < 4; ++j) {
            f32x2 ta = xlA[j] + xr2[j];
            ta = __builtin_elementwise_max(ta, ta * 0.2f);
            pA2 += ta * att2[j];
            f32x2 tb = xlB[j] + xr2[j];
            tb = __builtin_elementwise_max(tb, tb * 0.2f);
            pB2 += tb * att2[j];
        }
        float pA = pA2.x + pA2.y, pB = pB2.x + pB2.y;
        pA = dppadd<0xB1>(pA);
        pB = dppadd<0xB1>(pB);
        pA = dppadd<0x4E>(pA);
        pB = dppadd<0x4E>(pB);
        pA = dppadd<0x141>(pA);
        pB = dppadd<0x141>(pB);
        float wA = __builtin_amdgcn_exp2f(pA);
        float wB = (2 * p + 1 < deg) ? __builtin_amdgcn_exp2f(pB) : 0.0f;
        s += wA + wB;
        f32x2 wA2 = (f32x2){wA, wA}, wB2 = (f32x2){wB, wB};
#pragma unroll
        for (int j = 0; j < 4; ++j) {
            acc2[j] += wA2 * xlA[j];
            acc2[j] += wB2 * xlB[j];
        }
        cA = nA; cB = nB;
    }

    if (hv) {
        float inv = 1.0f / (s + 1e-16f);
        size_t ob = (size_t)i * HCC + off;
        uint4 rv = *(const uint4*)(resB + ob);
        f32x2 rr[4];
        bf8cvt2(rv, rr);
        ushort_t u[8];
#pragma unroll
        for (int j = 0; j < 4; ++j) {
            float v0 = acc2[j].x * inv + bias[off + 2 * j];
            float v1 = acc2[j].y * inv + bias[off + 2 * j + 1];
            v0 = v0 > 0.0f ? v0 : expm1f(v0);
            v1 = v1 > 0.0f ? v1 : expm1f(v1);
            u[2 * j]     = f2bf(v0 + rr[j].x);
            u[2 * j + 1] = f2bf(v1 + rr[j].y);
        }
        *(uint4*)(outB + ob) = *(uint4*)u;
    }
}

// ---------------- GATv2 H=1: 16-edge (2x8) pair pipeline, degree-descending order ----------------
__global__ __launch_bounds__(128) void gat1_kernel(
    const ushort_t* __restrict__ cat, const float* __restrict__ att,
    const float* __restrict__ bias, const float* __restrict__ res,
    float* __restrict__ out,
    const int* __restrict__ offsets, const int* __restrict__ srcs,
    const int* __restrict__ order, int n)
{
    int wid = (blockIdx.x * blockDim.x + threadIdx.x) >> 6;
    if (wid >= n) return;
    int lane = threadIdx.x & 63;
    int e8 = lane >> 3, c8 = lane & 7;
    int i = __builtin_amdgcn_readfirstlane(order[wid]);
    int beg = __builtin_amdgcn_readfirstlane(offsets[i]);
    int end = __builtin_amdgcn_readfirstlane(offsets[i + 1]);
    const char* catc = (const char*)cat;

    f32x2 xr2[4], att2[4];
    {
        uint4 v = *(const uint4*)(cat + (size_t)i * 128 + 64 + c8 * 8);
        bf8cvt2(v, xr2);
    }
#pragma unroll
    for (int j = 0; j < 4; ++j)
        att2[j] = (f32x2){att[c8 * 8 + 2 * j] * LOG2E, att[c8 * 8 + 2 * j + 1] * LOG2E};

    float s = 0.0f;
    f32x2 acc2[4];
#pragma unroll
    for (int j = 0; j < 4; ++j) acc2[j] = (f32x2){0.f, 0.f};

    // prologue: groups A (beg+e8) and B (beg+8+e8) in flight
    int pA = beg + e8, pB = beg + 8 + e8;
    bool vA = pA < end, vB = pB < end;
    uint4 a = *(const uint4*)(catc + (size_t)(uint_t)srcs[pA] + c8 * 16);
    uint4 b = *(const uint4*)(catc + (size_t)(uint_t)srcs[pB] + c8 * 16);

    for (int p0 = beg; p0 < end; p0 += 16) {
        uint4 na = a, nb = b;
        bool nvA = false, nvB = false;
        bool pre = (p0 + 16 < end);   // uniform
        if (pre) {
            int qA = p0 + 16 + e8, qB = p0 + 24 + e8;
            nvA = qA < end; nvB = qB < end;
            na = *(const uint4*)(catc + (size_t)(uint_t)srcs[qA] + c8 * 16);
            nb = *(const uint4*)(catc + (size_t)(uint_t)srcs[qB] + c8 * 16);
        }
        f32x2 xlA[4], xlB[4];
        bf8cvt2(a, xlA);
        bf8cvt2(b, xlB);
        f32x2 lA2 = (f32x2){0.f, 0.f}, lB2 = (f32x2){0.f, 0.f};
#pragma unroll
        for (int j = 0; j < 4; ++j) {
            f32x2 ta = xlA[j] + xr2[j];
            ta = __builtin_elementwise_max(ta, ta * 0.2f);
            lA2 += ta * att2[j];
            f32x2 tb = xlB[j] + xr2[j];
            tb = __builtin_elementwise_max(tb, tb * 0.2f);
            lB2 += tb * att2[j];
        }
        float lA = lA2.x + lA2.y, lB = lB2.x + lB2.y;
        lA = dppadd<0xB1>(lA);
        lB = dppadd<0xB1>(lB);
        lA = dppadd<0x4E>(lA);
        lB = dppadd<0x4E>(lB);
        lA = dppadd<0x141>(lA);
        lB = dppadd<0x141>(lB);
        float wA = vA ? __builtin_amdgcn_exp2f(lA) : 0.0f;
        float wB = vB ? __builtin_amdgcn_exp2f(lB) : 0.0f;
        s += wA + wB;
        f32x2 wA2 = (f32x2){wA, wA}, wB2 = (f32x2){wB, wB};
#pragma unroll
        for (int j = 0; j < 4; ++j) {
            acc2[j] += wA2 * xlA[j];
            acc2[j] += wB2 * xlB[j];
        }
        a = na; b = nb; vA = nvA; vB = nvB;
    }

    // cross-group reduce (8 groups of 8 lanes)
    s = dppadd<0x140>(s);
    s += __shfl_xor(s, 16, 64);
    s += __shfl_xor(s, 32, 64);
#pragma unroll
    for (int j = 0; j < 4; ++j) {
        acc2[j].x += __shfl_xor(acc2[j].x, 8, 64);
        acc2[j].y += __shfl_xor(acc2[j].y, 8, 64);
        acc2[j].x += __shfl_xor(acc2[j].x, 16, 64);
        acc2[j].y += __shfl_xor(acc2[j].y, 16, 64);
        acc2[j].x += __shfl_xor(acc2[j].x, 32, 64);
        acc2[j].y += __shfl_xor(acc2[j].y, 32, 64);
    }
    if (e8 == 0) {
        float inv = 1.0f / (s + 1e-16f);
        size_t ob = (size_t)i * CC + c8 * 8;
        float4 r0 = *(const float4*)(res + ob);
        float4 r1 = *(const float4*)(res + ob + 4);
        float rr[8] = {r0.x, r0.y, r0.z, r0.w, r1.x, r1.y, r1.z, r1.w};
        float av[8] = {acc2[0].x, acc2[0].y, acc2[1].x, acc2[1].y,
                       acc2[2].x, acc2[2].y, acc2[3].x, acc2[3].y};
#pragma unroll
        for (int j = 0; j < 8; ++j) {
            float v2 = av[j] * inv + bias[c8 * 8 + j];
            v2 = v2 > 0.0f ? v2 : expm1f(v2);
            av[j] = v2 + rr[j];
        }
        *(float4*)(out + ob) = make_float4(av[0], av[1], av[2], av[3]);
        *(float4*)(out + ob + 4) = make_float4(av[4], av[5], av[6], av[7]);
    }
}

// ---------------- pooling: 4 blocks per group (batch sorted), one atomic per block ----------------
__global__ __launch_bounds__(256) void pool_kernel(const float* __restrict__ h,
                                                   const int* __restrict__ batch,
                                                   float* __restrict__ pooled, int n) {
    int b = blockIdx.x;            // NG*4 blocks
    int g = b >> 2, qd = b & 3;
    int t = threadIdx.x;           // 256
    int w = t >> 6, lane = t & 63;
    int lo = 0, hi = n;
    while (lo < hi) { int mid = (lo + hi) >> 1; if (batch[mid] < g) lo = mid + 1; else hi = mid; }
    int start = lo;
    int hi2 = n;
    while (lo < hi2) { int mid = (lo + hi2) >> 1; if (batch[mid] < g + 1) lo = mid + 1; else hi2 = mid; }
    int endd = lo;
    int len = endd - start;
    int q0 = start + (len * qd) / 4;
    int q1 = start + (len * (qd + 1)) / 4;
    float acc = 0.0f;
    for (int r = q0 + w; r < q1; r += 4)
        acc += h[(size_t)r * 64 + lane];
    __shared__ float red[4][64];
    red[w][lane] = acc;
    __syncthreads();
    if (w == 0) {
        float v2 = red[0][lane] + red[1][lane] + red[2][lane] + red[3][lane];
        atomicAdd(&pooled[g * 64 + lane], v2);
    }
}

// ---------------- dense head: LDS-staged operands ----------------
__global__ __launch_bounds__(256) void head_kernel(const float* __restrict__ pooled,
                            const float* __restrict__ d1w, const float* __restrict__ d1b,
                            const float* __restrict__ bng, const float* __restrict__ bnb,
                            const float* __restrict__ bnm, const float* __restrict__ bnv,
                            const float* __restrict__ d2w, const float* __restrict__ d2b,
                            float* __restrict__ zout) {
    __shared__ float pl[64 * 64];   // 16 KB
    __shared__ float w1[64 * 64];   // 16 KB
    __shared__ float w2[64 * NCC];  // 4 KB
    __shared__ float z1[64 * 64];   // 16 KB
    int t = threadIdx.x;  // 256
    for (int i = t * 4; i < 64 * 64; i += 1024) {
        *(float4*)&pl[i] = *(const float4*)&pooled[i];
        *(float4*)&w1[i] = *(const float4*)&d1w[i];
    }
    for (int i = t * 4; i < 64 * NCC; i += 1024)
        *(float4*)&w2[i] = *(const float4*)&d2w[i];
    __syncthreads();
    for (int idx = t; idx < 64 * 64; idx += 256) {
        int r = idx >> 6, c = idx & 63;
        float acc = d1b[c];
        for (int k = 0; k < 64; ++k) acc += pl[r * 64 + k] * w1[k * 64 + c];
        acc = (acc - bnm[c]) / sqrtf(bnv[c] + 1e-5f) * bng[c] + bnb[c];
        z1[idx] = acc > 0.0f ? acc : 0.0f;
    }
    __syncthreads();
    for (int idx = t; idx < 64 * NCC; idx += 256) {
        int r = idx >> 4, c = idx & 15;
        float acc = d2b[c];
        for (int k = 0; k < 64; ++k) acc += z1[r * 64 + k] * w2[k * NCC + c];
        zout[idx] = acc;
    }
}

// ---------------- launcher ----------------

extern "C" void kernel_launch(void* const* d_in, const int* in_sizes, int n_in,
                              void* d_out, int out_size, void* d_ws, size_t ws_size,
                              hipStream_t stream) {
    const int N = NN, E = EE, C = CC, HC = HCC, NG = NGG;
    const int EN = E + N;

    const float* x     = (const float*)d_in[0];
    const int*   ei    = (const int*)d_in[1];
    const int*   batch = (const int*)d_in[2];
    const float* inp_w = (const float*)d_in[3];
    const float* inp_b = (const float*)d_in[4];
    const float* l0_wl = (const float*)d_in[5];
    const float* l0_bl = (const float*)d_in[6];
    const float* l0_wr = (const float*)d_in[7];
    const float* l0_br = (const float*)d_in[8];
    const float* l0_att = (const float*)d_in[9];
    const float* l0_bias = (const float*)d_in[10];
    const float* l1_wl = (const float*)d_in[11];
    const float* l1_bl = (const float*)d_in[12];
    const float* l1_wr = (const float*)d_in[13];
    const float* l1_br = (const float*)d_in[14];
    const float* l1_att = (const float*)d_in[15];
    const float* l1_bias = (const float*)d_in[16];
    const float* l2_wl = (const float*)d_in[17];
    const float* l2_bl = (const float*)d_in[18];
    const float* l2_wr = (const float*)d_in[19];
    const float* l2_br = (const float*)d_in[20];
    const float* l2_att = (const float*)d_in[21];
    const float* l2_bias = (const float*)d_in[22];
    const float* res_w = (const float*)d_in[23];
    const float* d1_w = (const float*)d_in[24];
    const float* d1_b = (const float*)d_in[25];
    const float* bn_g = (const float*)d_in[26];
    const float* bn_b = (const float*)d_in[27];
    const float* bn_m = (const float*)d_in[28];
    const float* bn_v = (const float*)d_in[29];
    const float* d2_w = (const float*)d_in[30];
    const float* d2_b = (const float*)d_in[31];

    float* out = (float*)d_out;

    char* ws = (char*)d_ws;
    size_t off = 0;
    auto alloc = [&](size_t bytes) -> void* {
        void* p = ws + off;
        off += (bytes + 255) & ~(size_t)255;
        return p;
    };
    ushort_t* bufH_b  = (ushort_t*)alloc((size_t)N * HC * 2);
    ushort_t* cat01_b = (ushort_t*)alloc((size_t)N * 768 * 2 + 2048);
    ushort_t* xres_b  = (ushort_t*)alloc((size_t)N * HC * 2);
    ushort_t* cat2_b  = (ushort_t*)alloc((size_t)N * 128 * 2);
    float*    bufRes  = (float*)alloc((size_t)N * C * 4);
    ushort_t* xb      = (ushort_t*)alloc((size_t)N * IND * 2);
    ushort_t* wBig    = (ushort_t*)alloc((size_t)WBIG * 2);
    ushort_t* wC1     = (ushort_t*)alloc((size_t)WC1 * 2);
    ushort_t* wC2     = (ushort_t*)alloc((size_t)WC2 * 2);
    float*    bBig    = (float*)alloc((size_t)1152 * 4);
    float*    bC1     = (float*)alloc((size_t)768 * 4);
    float*    bC2     = (float*)alloc((size_t)192 * 4);
    int*      counts  = (int*)alloc((size_t)N * 4);
    int*      cursor  = (int*)alloc((size_t)N * 4);
    int*      offsets = (int*)alloc((size_t)(N + 1) * 4);
    int*      srcs    = (int*)alloc((size_t)(EN + 32) * 4);  // s<<8 + 32-entry zeroed pad
    int*      blockSums = (int*)alloc((size_t)256 * 4);
    int*      dhist   = (int*)alloc((size_t)256 * 4);
    int*      dcur    = (int*)alloc((size_t)256 * 4);
    int*      order   = (int*)alloc((size_t)N * 4);
    float*    pooled  = (float*)alloc((size_t)NG * C * 4);

    const int SCAN_NB = (N + 255) / 256;   // 79

    zero_init_kernel<<<(N + 255) / 256, 256, 0, stream>>>(counts, srcs + EN, dhist,
                                                          pooled, N, NG * C);
    count_kernel<<<(E + 255) / 256, 256, 0, stream>>>(ei, counts, E);
    scan_local_kernel<<<SCAN_NB, 256, 0, stream>>>(counts, offsets, blockSums, dhist, N);
    scan_fixup_kernel<<<SCAN_NB, 256, 0, stream>>>(blockSums, offsets, cursor, N, SCAN_NB);
    dscan_kernel<<<1, 256, 0, stream>>>(dhist, dcur);
    order_kernel<<<SCAN_NB, 256, 0, stream>>>(counts, dcur, order, N);
    fill_kernel<<<(EN + 255) / 256, 256, 0, stream>>>(ei, cursor, srcs, E, N);
    prep_kernel<<<(PREP_TOTAL + 255) / 256, 256, 0, stream>>>(
        x, inp_w, l0_wl, l0_wr, l1_wl, l1_wr, l2_wl, l2_wr, res_w,
        inp_b, l0_bl, l0_br, l1_bl, l1_br, l2_bl, l2_br,
        wBig, wC1, wC2, xb, bBig, bC1, bC2);

    int mtiles = (N + 127) / 128;      // 157
    dim3 gblk(128);
    int gatBlocks = (N * 64 + 127) / 128;

    // fused: [x_res | l0_xl | l0_xr] = xb @ wBig (bf16 out; split at 384). 1413 blocks.
    gemm_mfma<<<dim3(mtiles, 9), dim3(256), 0, stream>>>(xb, wBig, bBig,
        nullptr, xres_b, HC, cat01_b, 768, 384, N, 1152, IND);
    gat6_kernel<<<gatBlocks, gblk, 0, stream>>>(cat01_b, l0_att, l0_bias,
                                                xres_b, bufH_b, offsets, srcs, order, N);
    // layer 1: [l1_xl | l1_xr] = h0 @ wC1. 942 blocks.
    gemm_mfma<<<dim3(mtiles, 6), dim3(256), 0, stream>>>(bufH_b, wC1, bC1,
        nullptr, nullptr, 0, cat01_b, 768, 0, N, 768, HC);
    gat6_kernel<<<gatBlocks, gblk, 0, stream>>>(cat01_b, l1_att, l1_bias,
                                                bufH_b, bufH_b, offsets, srcs, order, N);
    // fused: [res | l2_xl | l2_xr] = h1 @ wC2 (res fp32, rest bf16). 314 blocks.
    gemm_mfma<<<dim3(mtiles, 2), dim3(256), 0, stream>>>(bufH_b, wC2, bC2,
        bufRes, nullptr, C, cat2_b, 128, 64, N, 192, HC);
    gat1_kernel<<<gatBlocks, gblk, 0, stream>>>(cat2_b, l2_att, l2_bias,
                                                bufRes, out, offsets, srcs, order, N);
    // pooling + head
    pool_kernel<<<NG * 4, 256, 0, stream>>>(out, batch, pooled, N);
    head_kernel<<<1, 256, 0, stream>>>(pooled, d1_w, d1_b, bn_g, bn_b, bn_m, bn_v,
                                       d2_w, d2_b, out + (size_t)N * C);
}

// Round 13
// 366.085 us; speedup vs baseline: 1.2932x; 1.2932x over previous
//
#include <hip/hip_runtime.h>
#include <hip/hip_bf16.h>
#include <math.h>

#define NN 20000
#define EE 320000
#define IND 128
#define HH 6
#define CC 64
#define HCC 384
#define NCC 16
#define NGG 64

typedef __bf16 bf16x8 __attribute__((ext_vector_type(8)));
typedef float f32x4 __attribute__((ext_vector_type(4)));
typedef float f32x2 __attribute__((ext_vector_type(2)));
typedef unsigned short ushort_t;
typedef unsigned int uint_t;

#define LOG2E 1.44269504088896f

__device__ inline ushort_t f2bf(float f) {
    union { float f; uint_t u; } x; x.f = f;
    uint_t r = (x.u + 0x7FFF + ((x.u >> 16) & 1)) >> 16;
    return (ushort_t)r;
}
// 8 packed bf16 (uint4) -> 4 f32x2 (pairs) for packed-f32 VALU
__device__ inline void bf8cvt2(uint4 v, f32x2* f) {
    union { uint_t u; float x; } a, b;
    a.u = v.x << 16; b.u = v.x & 0xFFFF0000u; f[0] = (f32x2){a.x, b.x};
    a.u = v.y << 16; b.u = v.y & 0xFFFF0000u; f[1] = (f32x2){a.x, b.x};
    a.u = v.z << 16; b.u = v.z & 0xFFFF0000u; f[2] = (f32x2){a.x, b.x};
    a.u = v.w << 16; b.u = v.w & 0xFFFF0000u; f[3] = (f32x2){a.x, b.x};
}

// DPP cross-lane add (VALU, no DS pipe). CTRL: 0xB1=xor1, 0x4E=xor2,
// 0x141=row_half_mirror (==xor4 once quad-uniform), 0x140=row_mirror (==xor8).
template <int CTRL>
__device__ inline float dppadd(float x) {
    int y = __builtin_amdgcn_mov_dpp(__builtin_bit_cast(int, x), CTRL, 0xF, 0xF, true);
    return x + __builtin_bit_cast(float, y);
}

// async global->LDS: lane L writes lds+16*L
__device__ inline void load_lds16(const ushort_t* g, ushort_t* l) {
    __builtin_amdgcn_global_load_lds(
        (const __attribute__((address_space(1))) void*)g,
        (__attribute__((address_space(3))) void*)l, 16, 0, 0);
}

// bijective XCD swizzle (m204): consecutive logical ids land on the SAME XCD.
// lin = HW launch order (lin%8 -> XCD). Returns logical tile id.
__device__ inline int xcd_swz(int lin, int nwg) {
    int q = nwg >> 3, r = nwg & 7;
    int xc = lin & 7, j = lin >> 3;
    return (xc < r ? xc * (q + 1) : r * (q + 1) + (xc - r) * q) + j;
}

// ---------------- utility kernels ----------------

__global__ void zero_init_kernel(int* counts, int* srcs_tail,
                                 float* pooled, int n, int np) {
    int t = blockIdx.x * blockDim.x + threadIdx.x;
    if (t < n) counts[t] = 0;
    if (t < np) pooled[t] = 0.0f;
    if (t < 32) srcs_tail[t] = 0;    // pad covers gat1's 16-edge group over-read
}

__global__ void count_kernel(const int* __restrict__ ei, int* __restrict__ counts, int E) {
    int t = blockIdx.x * blockDim.x + threadIdx.x;
    if (t < E) atomicAdd(&counts[ei[E + t]], 1);
}

// distributed scan: phase 1 per-block exclusive scan of (counts+1); block totals out.
// NOTE (r12 lesson): NO degree-histogram atomics here — 20000 atomics onto ~40 hot
// counters serialized at 54us. Never scatter N-wide atomics onto a <=256-entry array.
__global__ __launch_bounds__(256) void scan_local_kernel(
    const int* __restrict__ counts, int* __restrict__ offsets,
    int* __restrict__ blockSums, int n) {
    __shared__ int lp[256];
    int t = threadIdx.x, b = blockIdx.x;
    int i = b * 256 + t;
    int v = (i < n) ? counts[i] + 1 : 0;
    lp[t] = v;
    __syncthreads();
    for (int o = 1; o < 256; o <<= 1) {
        int u = (t >= o) ? lp[t - o] : 0;
        __syncthreads();
        lp[t] += u;
        __syncthreads();
    }
    if (t == 255) blockSums[b] = lp[255];
    if (i < n) offsets[i] = lp[t] - v;   // block-local exclusive
}

// phase 2: add scanned block prefix, finalize offsets + cursor.
__global__ __launch_bounds__(256) void scan_fixup_kernel(
    const int* __restrict__ blockSums,
    int* __restrict__ offsets, int* __restrict__ cursor, int n, int nb) {
    __shared__ int red[256];
    int t = threadIdx.x, b = blockIdx.x;
    red[t] = (t < b) ? blockSums[t] : 0;
    __syncthreads();
    for (int o = 128; o > 0; o >>= 1) {
        if (t < o) red[t] += red[t + o];
        __syncthreads();
    }
    int prefix = red[0];
    int i = b * 256 + t;
    if (i < n) {
        int val = offsets[i] + prefix;
        offsets[i] = val;
        cursor[i] = val;
    }
    if (b == nb - 1 && t == 0) offsets[n] = prefix + blockSums[b];
}

// fill: single srcs array storing s<<8 (byte offset for 256B rows); gat6 derives *6.
__global__ void fill_kernel(const int* __restrict__ ei, int* __restrict__ cursor,
                            int* __restrict__ srcs, int E, int n) {
    int t = blockIdx.x * blockDim.x + threadIdx.x;
    if (t < E) {
        int s = ei[t];
        int d = ei[E + t];
        int slot = atomicAdd(&cursor[d], 1);
        srcs[slot] = s << 8;
    } else if (t < E + n) {
        int i = t - E;
        int slot = atomicAdd(&cursor[i], 1);
        srcs[slot] = i << 8;
    }
}

// ---------------- weight/input prep: fp32 -> bf16 TRANSPOSED ([N][K]) ----------------
#define WBIG (1152 * IND)
#define WC1 (768 * HCC)
#define WC2 (192 * HCC)
#define XB_N (NN * IND)
#define PREP_TOTAL (WBIG + WC1 + WC2 + XB_N + 1152 + 768 + 192)

__global__ void prep_kernel(const float* __restrict__ x, const float* __restrict__ inp_w,
    const float* __restrict__ l0wl, const float* __restrict__ l0wr,
    const float* __restrict__ l1wl, const float* __restrict__ l1wr,
    const float* __restrict__ l2wl, const float* __restrict__ l2wr,
    const float* __restrict__ resw,
    const float* __restrict__ inp_b,
    const float* __restrict__ l0bl, const float* __restrict__ l0br,
    const float* __restrict__ l1bl, const float* __restrict__ l1br,
    const float* __restrict__ l2bl, const float* __restrict__ l2br,
    ushort_t* wBig, ushort_t* wC1, ushort_t* wC2, ushort_t* xb,
    float* bBig, float* bC1, float* bC2)
{
    int i = blockIdx.x * blockDim.x + threadIdx.x;
    if (i >= PREP_TOTAL) return;
    if (i < WBIG) {
        int col = i >> 7, k = i & 127;
        float v;
        if (col < 384)      v = inp_w[k * 384 + col];
        else if (col < 768) v = l0wl[k * 384 + (col - 384)];
        else                v = l0wr[k * 384 + (col - 768)];
        wBig[i] = f2bf(v); return;
    }
    i -= WBIG;
    if (i < WC1) {
        int col = i / 384, k = i - col * 384;
        float v = col < 384 ? l1wl[k * 384 + col] : l1wr[k * 384 + (col - 384)];
        wC1[i] = f2bf(v); return;
    }
    i -= WC1;
    if (i < WC2) {
        int col = i / 384, k = i - col * 384;
        float v;
        if (col < 64)       v = resw[k * 64 + col];
        else if (col < 128) v = l2wl[k * 64 + (col - 64)];
        else                v = l2wr[k * 64 + (col - 128)];
        wC2[i] = f2bf(v); return;
    }
    i -= WC2;
    if (i < XB_N) { xb[i] = f2bf(x[i]); return; }
    i -= XB_N;
    if (i < 1152) {
        float v;
        if (i < 384)      v = inp_b[i];
        else if (i < 768) v = l0bl[i - 384];
        else              v = l0br[i - 768];
        bBig[i] = v; return;
    }
    i -= 1152;
    if (i < 768) { bC1[i] = i < 384 ? l1bl[i] : l1br[i - 384]; return; }
    i -= 768;
    if (i < 192) {
        float v;
        if (i < 64)       v = 0.0f;
        else if (i < 128) v = l2bl[i - 64];
        else              v = l2br[i - 128];
        bC2[i] = v; return;
    }
}

// ---------------- bf16 MFMA GEMM (128-tile, 4 waves): ALL gemms ----------------
// 128-tile grids (1413/942/314 blocks = 3-5/CU): cross-block TLP hides the k-loop
// prologue (m114). XCD swizzle groups same-A-panel blocks per XCD.
__global__ __launch_bounds__(256) void gemm_mfma(
    const ushort_t* __restrict__ A, const ushort_t* __restrict__ BT,
    const float* __restrict__ bias,
    float* __restrict__ Cf, ushort_t* __restrict__ Cb1, int ld1,
    ushort_t* __restrict__ Cb2, int ld2, int split,
    int M, int N, int K)
{
    __shared__ ushort_t Bs[2][2][128 * 32];
    int t = threadIdx.x;
    int w = t >> 6, L = t & 63;
    int nwg = gridDim.x * gridDim.y;
    int logical = xcd_swz(blockIdx.y * gridDim.x + blockIdx.x, nwg);
    int m0 = (logical / gridDim.y) * 128;     // A-sharing group consecutive -> same XCD
    int n0 = (logical % gridDim.y) * 128;
    int q = L >> 4, r16 = L & 15;

    f32x4 acc[2][8];
#pragma unroll
    for (int a = 0; a < 2; ++a)
#pragma unroll
        for (int b = 0; b < 8; ++b) acc[a][b] = (f32x4){0.f, 0.f, 0.f, 0.f};

    int lr = L >> 2;
    int lc = ((L & 3) ^ ((lr >> 1) & 3)) * 8;
    int rB0 = min(n0 + w * 32 + lr, N - 1);
    int rB1 = min(n0 + w * 32 + 16 + lr, N - 1);
    const ushort_t* gB0 = BT + (size_t)rB0 * K + lc;
    const ushort_t* gB1 = BT + (size_t)rB1 * K + lc;
    int oB0 = (w * 32) * 32;
    int oB1 = (w * 32 + 16) * 32;

    int rA0 = min(m0 + w * 32 + r16, M - 1);
    int rA1 = min(m0 + w * 32 + 16 + r16, M - 1);
    const ushort_t* pA0 = A + (size_t)rA0 * K + q * 8;
    const ushort_t* pA1 = A + (size_t)rA1 * K + q * 8;

    int sw = (q ^ ((r16 >> 1) & 3)) * 8;

    load_lds16(gB0, &Bs[0][0][oB0]);
    load_lds16(gB1, &Bs[0][0][oB1]);
    load_lds16(gB0 + 32, &Bs[0][1][oB0]);
    load_lds16(gB1 + 32, &Bs[0][1][oB1]);
    gB0 += 64; gB1 += 64;
    bf16x8 a0 = *(const bf16x8*)pA0;
    bf16x8 a2 = *(const bf16x8*)(pA0 + 32);
    bf16x8 a1 = *(const bf16x8*)pA1;
    bf16x8 a3 = *(const bf16x8*)(pA1 + 32);
    pA0 += 64; pA1 += 64;

    int buf = 0;
    for (int k0 = 0; k0 < K; k0 += 64) {
        __syncthreads();
        bool more = (k0 + 64 < K);
        if (more) {
            int nb = buf ^ 1;
            load_lds16(gB0, &Bs[nb][0][oB0]);
            load_lds16(gB1, &Bs[nb][0][oB1]);
            load_lds16(gB0 + 32, &Bs[nb][1][oB0]);
            load_lds16(gB1 + 32, &Bs[nb][1][oB1]);
            gB0 += 64; gB1 += 64;
        }
        bf16x8 na0, na1, na2, na3;
        if (more) {
            na0 = *(const bf16x8*)pA0;
            na2 = *(const bf16x8*)(pA0 + 32);
            na1 = *(const bf16x8*)pA1;
            na3 = *(const bf16x8*)(pA1 + 32);
            pA0 += 64; pA1 += 64;
        }
#pragma unroll
        for (int ct = 0; ct < 8; ++ct) {
            bf16x8 blo = *(const bf16x8*)&Bs[buf][0][(ct * 16 + r16) * 32 + sw];
            bf16x8 bhi = *(const bf16x8*)&Bs[buf][1][(ct * 16 + r16) * 32 + sw];
            // swapped operands: lane holds row (m0+..+r16), cols q*4+reg
            acc[0][ct] = __builtin_amdgcn_mfma_f32_16x16x32_bf16(blo, a0, acc[0][ct], 0, 0, 0);
            acc[1][ct] = __builtin_amdgcn_mfma_f32_16x16x32_bf16(blo, a1, acc[1][ct], 0, 0, 0);
            acc[0][ct] = __builtin_amdgcn_mfma_f32_16x16x32_bf16(bhi, a2, acc[0][ct], 0, 0, 0);
            acc[1][ct] = __builtin_amdgcn_mfma_f32_16x16x32_bf16(bhi, a3, acc[1][ct], 0, 0, 0);
        }
        if (more) { a0 = na0; a1 = na1; a2 = na2; a3 = na3; }
        buf ^= 1;
    }
#pragma unroll
    for (int rt = 0; rt < 2; ++rt) {
        int row = m0 + w * 32 + rt * 16 + r16;
        if (row >= M) continue;
#pragma unroll
        for (int ct = 0; ct < 8; ++ct) {
            int colb = n0 + ct * 16 + q * 4;
            if (colb >= N) continue;
            float4 bv = *(const float4*)(bias + colb);
            float v0 = acc[rt][ct][0] + bv.x;
            float v1 = acc[rt][ct][1] + bv.y;
            float v2 = acc[rt][ct][2] + bv.z;
            float v3 = acc[rt][ct][3] + bv.w;
            if (colb < split) {
                if (Cf) {
                    *(float4*)(Cf + (size_t)row * ld1 + colb) = make_float4(v0, v1, v2, v3);
                } else {
                    uint2 pk;
                    pk.x = (uint_t)f2bf(v0) | ((uint_t)f2bf(v1) << 16);
                    pk.y = (uint_t)f2bf(v2) | ((uint_t)f2bf(v3) << 16);
                    *(uint2*)(Cb1 + (size_t)row * ld1 + colb) = pk;
                }
            } else {
                uint2 pk;
                pk.x = (uint_t)f2bf(v0) | ((uint_t)f2bf(v1) << 16);
                pk.y = (uint_t)f2bf(v2) | ((uint_t)f2bf(v3) << 16);
                *(uint2*)(Cb2 + (size_t)row * ld2 + (colb - split)) = pk;
            }
        }
    }
}

// ---------------- GATv2 H=6: branchless 1-deep pair loop, srcs = s<<8 (derive *6) ----------------
// r12 lesson: degree-descending wid->order[wid] indirection was net ~0 (tail gain
// offset by lost node locality) while its CSR machinery cost ~104us in contended
// atomics. Natural node order is optimal here.
__global__ __launch_bounds__(128) void gat6_kernel(
    const ushort_t* __restrict__ cat, const float* __restrict__ att,
    const float* __restrict__ bias, const ushort_t* __restrict__ resB,
    ushort_t* __restrict__ outB,
    const int* __restrict__ offsets, const int* __restrict__ srcs, int n)
{
    int wid = (blockIdx.x * blockDim.x + threadIdx.x) >> 6;
    if (wid >= n) return;
    int lane = threadIdx.x & 63;
    int h = lane >> 3, c8 = lane & 7;
    bool hv = h < HH;
    int off = h * 64 + c8 * 8;
    int offL2 = (hv ? off : off - 384) * 2;   // BYTE offset; invalid lanes alias groups 0/1
    int i = wid;
    int beg = __builtin_amdgcn_readfirstlane(offsets[i]);
    int end = __builtin_amdgcn_readfirstlane(offsets[i + 1]);
    int deg = end - beg;
    int P = (deg + 1) >> 1;
    const char* catc = (const char*)cat;

    f32x2 xr2[4], att2[4];
    {
        uint4 v = *(const uint4*)(catc + (size_t)i * 1536 + 768 + offL2);
        bf8cvt2(v, xr2);
    }
#pragma unroll
    for (int j = 0; j < 4; ++j) {
        int o = (offL2 >> 1) + 2 * j;
        att2[j] = (f32x2){att[o] * LOG2E, att[o + 1] * LOG2E};
    }

    float s = 0.0f;
    f32x2 acc2[4];
#pragma unroll
    for (int j = 0; j < 4; ++j) acc2[j] = (f32x2){0.f, 0.f};

    int bA0 = srcs[beg] * 6, bB0 = srcs[beg + 1] * 6;   // s<<8 -> s*1536
    uint4 cA = *(const uint4*)(catc + (size_t)(uint_t)bA0 + offL2);
    uint4 cB = *(const uint4*)(catc + (size_t)(uint_t)bB0 + offL2);
    int iA1 = srcs[beg + 2] * 6, iB1 = srcs[beg + 3] * 6;

    for (int p = 0; p < P; ++p) {
        uint4 nA = cA, nB = cB;
        bool pre = (p + 1 < P);       // uniform branch: skip useless last prefetch
        if (pre) {
            nA = *(const uint4*)(catc + (size_t)(uint_t)iA1 + offL2);
            nB = *(const uint4*)(catc + (size_t)(uint_t)iB1 + offL2);
            iA1 = srcs[beg + 2 * p + 4] * 6;
            iB1 = srcs[beg + 2 * p + 5] * 6;
        }
        f32x2 xlA[4], xlB[4];
        bf8cvt2(cA, xlA);
        bf8cvt2(cB, xlB);
        f32x2 pA2 = (f32x2){0.f, 0.f}, pB2 = (f32x2){0.f, 0.f};
#pragma unroll
        for (int j = 0; j < 4; ++j) {
            f32x2 ta = xlA[j] + xr2[j];
            ta = __builtin_elementwise_max(ta, ta * 0.2f);
            pA2 += ta * att2[j];
            f32x2 tb = xlB[j] + xr2[j];
            tb = __builtin_elementwise_max(tb, tb * 0.2f);
            pB2 += tb * att2[j];
        }
        float pA = pA2.x + pA2.y, pB = pB2.x + pB2.y;
        pA = dppadd<0xB1>(pA);
        pB = dppadd<0xB1>(pB);
        pA = dppadd<0x4E>(pA);
        pB = dppadd<0x4E>(pB);
        pA = dppadd<0x141>(pA);
        pB = dppadd<0x141>(pB);
        float wA = __builtin_amdgcn_exp2f(pA);
        float wB = (2 * p + 1 < deg) ? __builtin_amdgcn_exp2f(pB) : 0.0f;
        s += wA + wB;
        f32x2 wA2 = (f32x2){wA, wA}, wB2 = (f32x2){wB, wB};
#pragma unroll
        for (int j = 0; j < 4; ++j) {
            acc2[j] += wA2 * xlA[j];
            acc2[j] += wB2 * xlB[j];
        }
        cA = nA; cB = nB;
    }

    if (hv) {
        float inv = 1.0f / (s + 1e-16f);
        size_t ob = (size_t)i * HCC + off;
        uint4 rv = *(const uint4*)(resB + ob);
        f32x2 rr[4];
        bf8cvt2(rv, rr);
        ushort_t u[8];
#pragma unroll
        for (int j = 0; j < 4; ++j) {
            float v0 = acc2[j].x * inv + bias[off + 2 * j];
            float v1 = acc2[j].y * inv + bias[off + 2 * j + 1];
            v0 = v0 > 0.0f ? v0 : expm1f(v0);
            v1 = v1 > 0.0f ? v1 : expm1f(v1);
            u[2 * j]     = f2bf(v0 + rr[j].x);
            u[2 * j + 1] = f2bf(v1 + rr[j].y);
        }
        *(uint4*)(outB + ob) = *(uint4*)u;
    }
}

// ---------------- GATv2 H=1: 16-edge (2x8) pair pipeline, gat6-style ----------------
__global__ __launch_bounds__(128) void gat1_kernel(
    const ushort_t* __restrict__ cat, const float* __restrict__ att,
    const float* __restrict__ bias, const float* __restrict__ res,
    float* __restrict__ out,
    const int* __restrict__ offsets, const int* __restrict__ srcs, int n)
{
    int wid = (blockIdx.x * blockDim.x + threadIdx.x) >> 6;
    if (wid >= n) return;
    int lane = threadIdx.x & 63;
    int e8 = lane >> 3, c8 = lane & 7;
    int i = wid;
    int beg = __builtin_amdgcn_readfirstlane(offsets[i]);
    int end = __builtin_amdgcn_readfirstlane(offsets[i + 1]);
    const char* catc = (const char*)cat;

    f32x2 xr2[4], att2[4];
    {
        uint4 v = *(const uint4*)(cat + (size_t)i * 128 + 64 + c8 * 8);
        bf8cvt2(v, xr2);
    }
#pragma unroll
    for (int j = 0; j < 4; ++j)
        att2[j] = (f32x2){att[c8 * 8 + 2 * j] * LOG2E, att[c8 * 8 + 2 * j + 1] * LOG2E};

    float s = 0.0f;
    f32x2 acc2[4];
#pragma unroll
    for (int j = 0; j < 4; ++j) acc2[j] = (f32x2){0.f, 0.f};

    // prologue: groups A (beg+e8) and B (beg+8+e8) in flight
    int pA = beg + e8, pB = beg + 8 + e8;
    bool vA = pA < end, vB = pB < end;
    uint4 a = *(const uint4*)(catc + (size_t)(uint_t)srcs[pA] + c8 * 16);
    uint4 b = *(const uint4*)(catc + (size_t)(uint_t)srcs[pB] + c8 * 16);

    for (int p0 = beg; p0 < end; p0 += 16) {
        uint4 na = a, nb = b;
        bool nvA = false, nvB = false;
        bool pre = (p0 + 16 < end);   // uniform
        if (pre) {
            int qA = p0 + 16 + e8, qB = p0 + 24 + e8;
            nvA = qA < end; nvB = qB < end;
            na = *(const uint4*)(catc + (size_t)(uint_t)srcs[qA] + c8 * 16);
            nb = *(const uint4*)(catc + (size_t)(uint_t)srcs[qB] + c8 * 16);
        }
        f32x2 xlA[4], xlB[4];
        bf8cvt2(a, xlA);
        bf8cvt2(b, xlB);
        f32x2 lA2 = (f32x2){0.f, 0.f}, lB2 = (f32x2){0.f, 0.f};
#pragma unroll
        for (int j = 0; j < 4; ++j) {
            f32x2 ta = xlA[j] + xr2[j];
            ta = __builtin_elementwise_max(ta, ta * 0.2f);
            lA2 += ta * att2[j];
            f32x2 tb = xlB[j] + xr2[j];
            tb = __builtin_elementwise_max(tb, tb * 0.2f);
            lB2 += tb * att2[j];
        }
        float lA = lA2.x + lA2.y, lB = lB2.x + lB2.y;
        lA = dppadd<0xB1>(lA);
        lB = dppadd<0xB1>(lB);
        lA = dppadd<0x4E>(lA);
        lB = dppadd<0x4E>(lB);
        lA = dppadd<0x141>(lA);
        lB = dppadd<0x141>(lB);
        float wA = vA ? __builtin_amdgcn_exp2f(lA) : 0.0f;
        float wB = vB ? __builtin_amdgcn_exp2f(lB) : 0.0f;
        s += wA + wB;
        f32x2 wA2 = (f32x2){wA, wA}, wB2 = (f32x2){wB, wB};
#pragma unroll
        for (int j = 0; j < 4; ++j) {
            acc2[j] += wA2 * xlA[j];
            acc2[j] += wB2 * xlB[j];
        }
        a = na; b = nb; vA = nvA; vB = nvB;
    }

    // cross-group reduce (8 groups of 8 lanes)
    s = dppadd<0x140>(s);
    s += __shfl_xor(s, 16, 64);
    s += __shfl_xor(s, 32, 64);
#pragma unroll
    for (int j = 0; j < 4; ++j) {
        acc2[j].x += __shfl_xor(acc2[j].x, 8, 64);
        acc2[j].y += __shfl_xor(acc2[j].y, 8, 64);
        acc2[j].x += __shfl_xor(acc2[j].x, 16, 64);
        acc2[j].y += __shfl_xor(acc2[j].y, 16, 64);
        acc2[j].x += __shfl_xor(acc2[j].x, 32, 64);
        acc2[j].y += __shfl_xor(acc2[j].y, 32, 64);
    }
    if (e8 == 0) {
        float inv = 1.0f / (s + 1e-16f);
        size_t ob = (size_t)i * CC + c8 * 8;
        float4 r0 = *(const float4*)(res + ob);
        float4 r1 = *(const float4*)(res + ob + 4);
        float rr[8] = {r0.x, r0.y, r0.z, r0.w, r1.x, r1.y, r1.z, r1.w};
        float av[8] = {acc2[0].x, acc2[0].y, acc2[1].x, acc2[1].y,
                       acc2[2].x, acc2[2].y, acc2[3].x, acc2[3].y};
#pragma unroll
        for (int j = 0; j < 8; ++j) {
            float v2 = av[j] * inv + bias[c8 * 8 + j];
            v2 = v2 > 0.0f ? v2 : expm1f(v2);
            av[j] = v2 + rr[j];
        }
        *(float4*)(out + ob) = make_float4(av[0], av[1], av[2], av[3]);
        *(float4*)(out + ob + 4) = make_float4(av[4], av[5], av[6], av[7]);
    }
}

// ---------------- pooling: 4 blocks per group (batch sorted), one atomic per block ----------------
__global__ __launch_bounds__(256) void pool_kernel(const float* __restrict__ h,
                                                   const int* __restrict__ batch,
                                                   float* __restrict__ pooled, int n) {
    int b = blockIdx.x;            // NG*4 blocks
    int g = b >> 2, qd = b & 3;
    int t = threadIdx.x;           // 256
    int w = t >> 6, lane = t & 63;
    int lo = 0, hi = n;
    while (lo < hi) { int mid = (lo + hi) >> 1; if (batch[mid] < g) lo = mid + 1; else hi = mid; }
    int start = lo;
    int hi2 = n;
    while (lo < hi2) { int mid = (lo + hi2) >> 1; if (batch[mid] < g + 1) lo = mid + 1; else hi2 = mid; }
    int endd = lo;
    int len = endd - start;
    int q0 = start + (len * qd) / 4;
    int q1 = start + (len * (qd + 1)) / 4;
    float acc = 0.0f;
    for (int r = q0 + w; r < q1; r += 4)
        acc += h[(size_t)r * 64 + lane];
    __shared__ float red[4][64];
    red[w][lane] = acc;
    __syncthreads();
    if (w == 0) {
        float v2 = red[0][lane] + red[1][lane] + red[2][lane] + red[3][lane];
        atomicAdd(&pooled[g * 64 + lane], v2);
    }
}

// ---------------- dense head: LDS-staged operands ----------------
__global__ __launch_bounds__(256) void head_kernel(const float* __restrict__ pooled,
                            const float* __restrict__ d1w, const float* __restrict__ d1b,
                            const float* __restrict__ bng, const float* __restrict__ bnb,
                            const float* __restrict__ bnm, const float* __restrict__ bnv,
                            const float* __restrict__ d2w, const float* __restrict__ d2b,
                            float* __restrict__ zout) {
    __shared__ float pl[64 * 64];   // 16 KB
    __shared__ float w1[64 * 64];   // 16 KB
    __shared__ float w2[64 * NCC];  // 4 KB
    __shared__ float z1[64 * 64];   // 16 KB
    int t = threadIdx.x;  // 256
    for (int i = t * 4; i < 64 * 64; i += 1024) {
        *(float4*)&pl[i] = *(const float4*)&pooled[i];
        *(float4*)&w1[i] = *(const float4*)&d1w[i];
    }
    for (int i = t * 4; i < 64 * NCC; i += 1024)
        *(float4*)&w2[i] = *(const float4*)&d2w[i];
    __syncthreads();
    for (int idx = t; idx < 64 * 64; idx += 256) {
        int r = idx >> 6, c = idx & 63;
        float acc = d1b[c];
        for (int k = 0; k < 64; ++k) acc += pl[r * 64 + k] * w1[k * 64 + c];
        acc = (acc - bnm[c]) / sqrtf(bnv[c] + 1e-5f) * bng[c] + bnb[c];
        z1[idx] = acc > 0.0f ? acc : 0.0f;
    }
    __syncthreads();
    for (int idx = t; idx < 64 * NCC; idx += 256) {
        int r = idx >> 4, c = idx & 15;
        float acc = d2b[c];
        for (int k = 0; k < 64; ++k) acc += z1[r * 64 + k] * w2[k * NCC + c];
        zout[idx] = acc;
    }
}

// ---------------- launcher ----------------

extern "C" void kernel_launch(void* const* d_in, const int* in_sizes, int n_in,
                              void* d_out, int out_size, void* d_ws, size_t ws_size,
                              hipStream_t stream) {
    const int N = NN, E = EE, C = CC, HC = HCC, NG = NGG;
    const int EN = E + N;

    const float* x     = (const float*)d_in[0];
    const int*   ei    = (const int*)d_in[1];
    const int*   batch = (const int*)d_in[2];
    const float* inp_w = (const float*)d_in[3];
    const float* inp_b = (const float*)d_in[4];
    const float* l0_wl = (const float*)d_in[5];
    const float* l0_bl = (const float*)d_in[6];
    const float* l0_wr = (const float*)d_in[7];
    const float* l0_br = (const float*)d_in[8];
    const float* l0_att = (const float*)d_in[9];
    const float* l0_bias = (const float*)d_in[10];
    const float* l1_wl = (const float*)d_in[11];
    const float* l1_bl = (const float*)d_in[12];
    const float* l1_wr = (const float*)d_in[13];
    const float* l1_br = (const float*)d_in[14];
    const float* l1_att = (const float*)d_in[15];
    const float* l1_bias = (const float*)d_in[16];
    const float* l2_wl = (const float*)d_in[17];
    const float* l2_bl = (const float*)d_in[18];
    const float* l2_wr = (const float*)d_in[19];
    const float* l2_br = (const float*)d_in[20];
    const float* l2_att = (const float*)d_in[21];
    const float* l2_bias = (const float*)d_in[22];
    const float* res_w = (const float*)d_in[23];
    const float* d1_w = (const float*)d_in[24];
    const float* d1_b = (const float*)d_in[25];
    const float* bn_g = (const float*)d_in[26];
    const float* bn_b = (const float*)d_in[27];
    const float* bn_m = (const float*)d_in[28];
    const float* bn_v = (const float*)d_in[29];
    const float* d2_w = (const float*)d_in[30];
    const float* d2_b = (const float*)d_in[31];

    float* out = (float*)d_out;

    char* ws = (char*)d_ws;
    size_t off = 0;
    auto alloc = [&](size_t bytes) -> void* {
        void* p = ws + off;
        off += (bytes + 255) & ~(size_t)255;
        return p;
    };
    ushort_t* bufH_b  = (ushort_t*)alloc((size_t)N * HC * 2);
    ushort_t* cat01_b = (ushort_t*)alloc((size_t)N * 768 * 2 + 2048);
    ushort_t* xres_b  = (ushort_t*)alloc((size_t)N * HC * 2);
    ushort_t* cat2_b  = (ushort_t*)alloc((size_t)N * 128 * 2);
    float*    bufRes  = (float*)alloc((size_t)N * C * 4);
    ushort_t* xb      = (ushort_t*)alloc((size_t)N * IND * 2);
    ushort_t* wBig    = (ushort_t*)alloc((size_t)WBIG * 2);
    ushort_t* wC1     = (ushort_t*)alloc((size_t)WC1 * 2);
    ushort_t* wC2     = (ushort_t*)alloc((size_t)WC2 * 2);
    float*    bBig    = (float*)alloc((size_t)1152 * 4);
    float*    bC1     = (float*)alloc((size_t)768 * 4);
    float*    bC2     = (float*)alloc((size_t)192 * 4);
    int*      counts  = (int*)alloc((size_t)N * 4);
    int*      cursor  = (int*)alloc((size_t)N * 4);
    int*      offsets = (int*)alloc((size_t)(N + 1) * 4);
    int*      srcs    = (int*)alloc((size_t)(EN + 32) * 4);  // s<<8 + 32-entry zeroed pad
    int*      blockSums = (int*)alloc((size_t)256 * 4);
    float*    pooled  = (float*)alloc((size_t)NG * C * 4);

    const int SCAN_NB = (N + 255) / 256;   // 79

    zero_init_kernel<<<(N + 255) / 256, 256, 0, stream>>>(counts, srcs + EN,
                                                          pooled, N, NG * C);
    count_kernel<<<(E + 255) / 256, 256, 0, stream>>>(ei, counts, E);
    scan_local_kernel<<<SCAN_NB, 256, 0, stream>>>(counts, offsets, blockSums, N);
    scan_fixup_kernel<<<SCAN_NB, 256, 0, stream>>>(blockSums, offsets, cursor, N, SCAN_NB);
    fill_kernel<<<(EN + 255) / 256, 256, 0, stream>>>(ei, cursor, srcs, E, N);
    prep_kernel<<<(PREP_TOTAL + 255) / 256, 256, 0, stream>>>(
        x, inp_w, l0_wl, l0_wr, l1_wl, l1_wr, l2_wl, l2_wr, res_w,
        inp_b, l0_bl, l0_br, l1_bl, l1_br, l2_bl, l2_br,
        wBig, wC1, wC2, xb, bBig, bC1, bC2);

    int mtiles = (N + 127) / 128;      // 157
    dim3 gblk(128);
    int gatBlocks = (N * 64 + 127) / 128;

    // fused: [x_res | l0_xl | l0_xr] = xb @ wBig (bf16 out; split at 384). 1413 blocks.
    gemm_mfma<<<dim3(mtiles, 9), dim3(256), 0, stream>>>(xb, wBig, bBig,
        nullptr, xres_b, HC, cat01_b, 768, 384, N, 1152, IND);
    gat6_kernel<<<gatBlocks, gblk, 0, stream>>>(cat01_b, l0_att, l0_bias,
                                                xres_b, bufH_b, offsets, srcs, N);
    // layer 1: [l1_xl | l1_xr] = h0 @ wC1. 942 blocks.
    gemm_mfma<<<dim3(mtiles, 6), dim3(256), 0, stream>>>(bufH_b, wC1, bC1,
        nullptr, nullptr, 0, cat01_b, 768, 0, N, 768, HC);
    gat6_kernel<<<gatBlocks, gblk, 0, stream>>>(cat01_b, l1_att, l1_bias,
                                                bufH_b, bufH_b, offsets, srcs, N);
    // fused: [res | l2_xl | l2_xr] = h1 @ wC2 (res fp32, rest bf16). 314 blocks.
    gemm_mfma<<<dim3(mtiles, 2), dim3(256), 0, stream>>>(bufH_b, wC2, bC2,
        bufRes, nullptr, C, cat2_b, 128, 64, N, 192, HC);
    gat1_kernel<<<gatBlocks, gblk, 0, stream>>>(cat2_b, l2_att, l2_bias,
                                                bufRes, out, offsets, srcs, N);
    // pooling + head
    pool_kernel<<<NG * 4, 256, 0, stream>>>(out, batch, pooled, N);
    head_kernel<<<1, 256, 0, stream>>>(pooled, d1_w, d1_b, bn_g, bn_b, bn_m, bn_v,
                                       d2_w, d2_b, out + (size_t)N * C);
}